// Round 3
// baseline (3863.281 us; speedup 1.0000x reference)
//
#include <hip/hip_runtime.h>
#include <hip/hip_bf16.h>

#define N_NODES 10000
#define N_EDGES 40000
#define NLAYERS 5

typedef __bf16 bf16x8 __attribute__((ext_vector_type(8)));
typedef __bf16 bf16x4 __attribute__((ext_vector_type(4)));
typedef float  f32x4  __attribute__((ext_vector_type(4)));

__device__ __forceinline__ bf16x8 cvt8(float4 a, float4 b) {
    bf16x8 r;
    r[0] = (__bf16)a.x; r[1] = (__bf16)a.y; r[2] = (__bf16)a.z; r[3] = (__bf16)a.w;
    r[4] = (__bf16)b.x; r[5] = (__bf16)b.y; r[6] = (__bf16)b.z; r[7] = (__bf16)b.w;
    return r;
}

__device__ __forceinline__ void gload_lds16(const void* g, void* l) {
    __builtin_amdgcn_global_load_lds(
        (const __attribute__((address_space(1))) void*)g,
        (__attribute__((address_space(3))) void*)l, 16, 0, 0);
}

// ---------------- f32 -> bf16 conversion (8 elems/thread) ----------------
__global__ __launch_bounds__(256) void cvt_chunks(
    const float* __restrict__ s, __bf16* __restrict__ d,
    long chunk, long dstStride, long total8)
{
    for (long i = (long)blockIdx.x * blockDim.x + threadIdx.x; i < total8;
         i += (long)gridDim.x * blockDim.x) {
        long e = i * 8;
        long ch = e / chunk;
        long r  = e - ch * chunk;
        float4 a = *(const float4*)(s + e);
        float4 b = *(const float4*)(s + e + 4);
        *(bf16x8*)(d + ch * dstStride + r) = cvt8(a, b);
    }
}

// ---------------- LDS-staged bf16 GEMM: C = A[MxK] @ W[NcxK]^T ----------------
// tile 128x64, BK=64, 256 threads (4 waves, 2x2), XOR-swizzled LDS (both sides).
// MODE 0: f32 out. MODE 1: bf16 out. MODE 2: bf16 out with QKV transpose remap
//   (cols 0..511 -> Q^T [a][h], 512..1023 -> K^T [a][h], 1024..1535 -> V [h][a]).
template<int MODE>
__global__ __launch_bounds__(256) void gemm_lds(
    const __bf16* __restrict__ A, const __bf16* __restrict__ W,
    float* __restrict__ Cf, __bf16* __restrict__ Ch,
    int M, int K, int ldc, int coloff)
{
    __shared__ __bf16 As[128 * 64];   // 16 KB
    __shared__ __bf16 Wsh[64 * 64];   // 8 KB
    const int tid = threadIdx.x;
    const int ln  = tid & 63;
    const int wv  = tid >> 6;
    const int wr  = wv >> 1, wc = wv & 1;
    const int brow0 = blockIdx.x * 128;
    const int colb0 = blockIdx.y * 64;

    const int srow = ln >> 3;
    const int scol = ((ln & 7) ^ srow) * 8;

    const int fr = ln & 15;
    const int kq = ln >> 4;
    char* asb = (char*)As;
    char* wsb = (char*)Wsh;

    f32x4 acc[4][2];
    #pragma unroll
    for (int m = 0; m < 4; ++m)
        #pragma unroll
        for (int n = 0; n < 2; ++n) acc[m][n] = (f32x4){0.f, 0.f, 0.f, 0.f};

    const int nt = K >> 6;
    for (int t = 0; t < nt; ++t) {
        const int kk0 = t << 6;
        if (t) __syncthreads();
        #pragma unroll
        for (int c = 0; c < 4; ++c) {
            int ch = wv * 4 + c;
            int grow = brow0 + ch * 8 + srow;
            if (grow >= M) grow = M - 1;
            gload_lds16(A + (size_t)grow * K + kk0 + scol, asb + ch * 1024);
        }
        #pragma unroll
        for (int c = 0; c < 2; ++c) {
            int ch = wv * 2 + c;
            int grow = colb0 + ch * 8 + srow;
            gload_lds16(W + (size_t)grow * K + kk0 + scol, wsb + ch * 1024);
        }
        __syncthreads();
        #pragma unroll
        for (int ks = 0; ks < 2; ++ks) {
            const int kb = ks * 64 + kq * 16;
            const int sw = (fr & 7) << 4;
            bf16x8 af[4], wf[2];
            #pragma unroll
            for (int m = 0; m < 4; ++m) {
                int row = wr * 64 + m * 16 + fr;
                af[m] = *(const bf16x8*)(asb + row * 128 + (kb ^ sw));
            }
            #pragma unroll
            for (int n = 0; n < 2; ++n) {
                int row = wc * 32 + n * 16 + fr;
                wf[n] = *(const bf16x8*)(wsb + row * 128 + (kb ^ sw));
            }
            #pragma unroll
            for (int m = 0; m < 4; ++m)
                #pragma unroll
                for (int n = 0; n < 2; ++n)
                    acc[m][n] = __builtin_amdgcn_mfma_f32_16x16x32_bf16(
                        af[m], wf[n], acc[m][n], 0, 0, 0);
        }
    }

    int ocol[2];
    #pragma unroll
    for (int n = 0; n < 2; ++n) {
        int c = coloff + colb0 + wc * 32 + fr + n * 16;
        if (MODE == 2) {
            if (c < 512)        c = ((c & 15) << 5) | (c >> 4);
            else if (c < 1024)  { int c2 = c - 512; c = 512 + (((c2 & 15) << 5) | (c2 >> 4)); }
        }
        ocol[n] = c;
    }

    const int rq = (ln >> 4) * 4;
    #pragma unroll
    for (int m = 0; m < 4; ++m) {
        #pragma unroll
        for (int rr = 0; rr < 4; ++rr) {
            int orow = brow0 + wr * 64 + m * 16 + rq + rr;
            if (orow < M) {
                size_t base = (size_t)orow * ldc;
                #pragma unroll
                for (int n = 0; n < 2; ++n) {
                    if (MODE == 0) Cf[base + ocol[n]] = acc[m][n][rr];
                    else           Ch[base + ocol[n]] = (__bf16)acc[m][n][rr];
                }
            }
        }
    }
}

// ---------------- per-edge attention via MFMA, one wave per edge ----------------
// qkv layout per node (1536 bf16): Q^T[16a][32h] | K^T[16a][32h] | V[32h][16b].
// alphaT[b][a] = sum_h K^T[b][h] * Q[h][a]  (one 16x16x32 MFMA)
// softmax over b (regs + lanes l^16, l^32), then PV via two zero-padded
// 16x16x32 MFMAs (lane-groups 0-1 carry att/V, groups 2-3 carry zeros).
__global__ __launch_bounds__(256) void edge_attn(
    const int* __restrict__ eidx, const __bf16* __restrict__ qkv,
    float* __restrict__ attn)
{
    const int lane = threadIdx.x & 63;
    int e = __builtin_amdgcn_readfirstlane(blockIdx.x * 4 + (threadIdx.x >> 6));
    const int s = eidx[e];
    const int d = eidx[N_EDGES + e];
    const int fr = lane & 15;
    const int G  = lane >> 4;

    const __bf16* qT = qkv + (size_t)d * 1536;
    const __bf16* kT = qkv + (size_t)s * 1536 + 512;
    const __bf16* vp = qkv + (size_t)s * 1536 + 1024;

    bf16x8 kf = *(const bf16x8*)(kT + fr * 32 + G * 8);
    bf16x8 qf = *(const bf16x8*)(qT + fr * 32 + G * 8);
    const f32x4 zero = {0.f, 0.f, 0.f, 0.f};
    f32x4 al = __builtin_amdgcn_mfma_f32_16x16x32_bf16(kf, qf, zero, 0, 0, 0);
    // lane holds alphaT[b = G*4+r][a = fr], r = 0..3

    float mx = fmaxf(fmaxf(al[0], al[1]), fmaxf(al[2], al[3]));
    mx = fmaxf(mx, __shfl_xor(mx, 16));
    mx = fmaxf(mx, __shfl_xor(mx, 32));
    float p[4];
    #pragma unroll
    for (int r = 0; r < 4; ++r) p[r] = __expf((al[r] - mx) * 0.25f);
    float sum = p[0] + p[1] + p[2] + p[3];
    sum += __shfl_xor(sum, 16);
    sum += __shfl_xor(sum, 32);
    const float inv = 1.f / sum;

    // Build PV A-fragment: lane needs att[a=fr][b = G*8+j], j=0..7 (G<2), else 0.
    // Source of (a, b) is lane fr + (b>>2)*16, reg b&3 == j&3.
    bf16x8 paf;
    #pragma unroll
    for (int j = 0; j < 8; ++j) {
        int srcLane = fr + ((G * 8 + j) >> 2) * 16;
        float v = __shfl(p[j & 3], srcLane);
        paf[j] = (G < 2) ? (__bf16)(v * inv) : (__bf16)0.f;
    }

    float* ab = attn + (size_t)d * 512;
    #pragma unroll
    for (int hb = 0; hb < 2; ++hb) {
        bf16x8 vf = {0, 0, 0, 0, 0, 0, 0, 0};
        if (G < 2) vf = *(const bf16x8*)(vp + (hb * 16 + fr) * 16 + G * 8);
        f32x4 msg = __builtin_amdgcn_mfma_f32_16x16x32_bf16(paf, vf, zero, 0, 0, 0);
        // lane holds msg[a = G*4+r][h = hb*16+fr]; store at attn[d][h*16+a]
        #pragma unroll
        for (int r = 0; r < 4; ++r)
            atomicAdd(ab + (hb * 16 + fr) * 16 + G * 4 + r, msg[r]);
    }
}

// ---------------- fused residual + LayerNorm ----------------
__global__ __launch_bounds__(256) void ln_fused(
    const float* __restrict__ x, const __bf16* __restrict__ tb,
    const float* __restrict__ tf, const float* __restrict__ bias,
    const float* __restrict__ g, const float* __restrict__ b,
    float* __restrict__ outf, __bf16* __restrict__ outb)
{
    int wv = threadIdx.x >> 6;
    int lane = threadIdx.x & 63;
    int row = blockIdx.x * 4 + wv;
    int c = lane * 4;
    size_t off = (size_t)row * 256 + c;

    float4 v = *(const float4*)(x + off);
    float4 u = *(const float4*)(tf + off);
    v.x += u.x; v.y += u.y; v.z += u.z; v.w += u.w;
    if (tb) {
        bf16x4 w = *(const bf16x4*)(tb + off);
        v.x += (float)w[0]; v.y += (float)w[1]; v.z += (float)w[2]; v.w += (float)w[3];
    }
    float4 bi = *(const float4*)(bias + c);
    v.x += bi.x; v.y += bi.y; v.z += bi.z; v.w += bi.w;

    float sum = v.x + v.y + v.z + v.w;
    float sq  = v.x*v.x + v.y*v.y + v.z*v.z + v.w*v.w;
    #pragma unroll
    for (int m = 1; m < 64; m <<= 1) {
        sum += __shfl_xor(sum, m);
        sq  += __shfl_xor(sq,  m);
    }
    float mean = sum * (1.f / 256.f);
    float var  = sq * (1.f / 256.f) - mean * mean;
    float invs = rsqrtf(var + 1e-5f);

    float4 gg = *(const float4*)(g + c);
    float4 bb = *(const float4*)(b + c);
    float4 o;
    o.x = (v.x - mean) * invs * gg.x + bb.x;
    o.y = (v.y - mean) * invs * gg.y + bb.y;
    o.z = (v.z - mean) * invs * gg.z + bb.z;
    o.w = (v.w - mean) * invs * gg.w + bb.w;
    *(float4*)(outf + off) = o;
    if (outb) {
        bf16x4 ob;
        ob[0] = (__bf16)o.x; ob[1] = (__bf16)o.y;
        ob[2] = (__bf16)o.z; ob[3] = (__bf16)o.w;
        *(bf16x4*)(outb + off) = ob;
    }
}

extern "C" void kernel_launch(void* const* d_in, const int* in_sizes, int n_in,
                              void* d_out, int out_size, void* d_ws, size_t ws_size,
                              hipStream_t stream)
{
    const int*   eidx = (const int*)  d_in[0];
    const float* x_in = (const float*)d_in[1];
    const float* We   = (const float*)d_in[2];
    const float* Wq   = (const float*)d_in[3];
    const float* Wk   = (const float*)d_in[4];
    const float* Wv   = (const float*)d_in[5];
    const float* Wo   = (const float*)d_in[6];
    const float* bo   = (const float*)d_in[7];
    const float* lng  = (const float*)d_in[8];
    const float* lnb  = (const float*)d_in[9];
    const float* mlpW = (const float*)d_in[10];
    const float* mlpb = (const float*)d_in[11];
    float* out = (float*)d_out;

    char* p = (char*)d_ws;
    __bf16* wE   = (__bf16*)p; p += (size_t)10 * 65536  * 2;
    __bf16* wQKV = (__bf16*)p; p += (size_t)10 * 393216 * 2;
    __bf16* wO   = (__bf16*)p; p += (size_t)10 * 131072 * 2;
    __bf16* wM   = (__bf16*)p; p += (size_t)5  * 65536  * 2;
    __bf16* qkv  = (__bf16*)p; p += (size_t)N_NODES * 1536 * 2;
    float*  attn = (float*) p; p += (size_t)N_NODES * 512 * 4;
    __bf16* xeb  = (__bf16*)p; p += (size_t)N_NODES * 256 * 2;
    float*  xbf  = (float*) p; p += (size_t)N_NODES * 256 * 4;
    __bf16* xbb  = (__bf16*)p; p += (size_t)N_NODES * 256 * 2;
    if ((size_t)(p - (char*)d_ws) > ws_size) return;
    float*  h2      = attn;           // alias: attn f32 dead after cvt
    __bf16* attn_bf = qkv;            // alias: qkv dead after edge_attn

    dim3 blk(256);
    auto cvtg = [](long total8) { long g = (total8 + 255) / 256; return dim3((unsigned)(g > 2048 ? 2048 : g)); };

    cvt_chunks<<<cvtg(81920), blk, 0, stream>>>(We,   wE,            65536,  65536, 81920);
    cvt_chunks<<<cvtg(163840), blk, 0, stream>>>(Wq,  wQKV,          131072, 393216, 163840);
    cvt_chunks<<<cvtg(163840), blk, 0, stream>>>(Wk,  wQKV + 131072, 131072, 393216, 163840);
    cvt_chunks<<<cvtg(163840), blk, 0, stream>>>(Wv,  wQKV + 262144, 131072, 393216, 163840);
    cvt_chunks<<<cvtg(163840), blk, 0, stream>>>(Wo,  wO,            131072, 131072, 163840);
    cvt_chunks<<<cvtg(40960), blk, 0, stream>>>(mlpW, wM,            65536,  65536, 40960);
    cvt_chunks<<<cvtg(320000), blk, 0, stream>>>(x_in, xbb,          2560000, 2560000, 320000);

    dim3 gN256(79, 4);
    dim3 gQKV(79, 24);

    const float* xcur_f = x_in;
    int step = 0;
    for (int l = 0; l < NLAYERS; ++l) {
        for (int s = 0; s < 2; ++s) {
            size_t ls = (size_t)(l * 2 + s);
            gemm_lds<1><<<gN256, blk, 0, stream>>>(xbb, wE + ls * 65536, nullptr, xeb,
                                                   N_NODES, 256, 256, 0);
            gemm_lds<2><<<gQKV, blk, 0, stream>>>(xeb, wQKV + ls * 393216, nullptr, qkv,
                                                  N_NODES, 256, 1536, 0);
            hipMemsetAsync(attn, 0, (size_t)N_NODES * 512 * 4, stream);
            edge_attn<<<dim3(N_EDGES / 4), blk, 0, stream>>>(eidx, qkv, attn);
            cvt_chunks<<<cvtg(640000), blk, 0, stream>>>(attn, attn_bf, 5120000, 5120000, 640000);
            gemm_lds<0><<<gN256, blk, 0, stream>>>(attn_bf, wO + ls * 131072, h2, nullptr,
                                                   N_NODES, 512, 256, 0);
            bool last = (step == 14);
            ln_fused<<<dim3(2500), blk, 0, stream>>>(xcur_f, xeb, h2, bo + ls * 256,
                                                     lng + (size_t)(l * 3 + s) * 256,
                                                     lnb + (size_t)(l * 3 + s) * 256,
                                                     last ? out : xbf, last ? nullptr : xbb);
            xcur_f = xbf; ++step;
        }
        gemm_lds<0><<<gN256, blk, 0, stream>>>(xbb, wM + (size_t)l * 65536, h2, nullptr,
                                               N_NODES, 256, 256, 0);
        bool last = (step == 14);
        ln_fused<<<dim3(2500), blk, 0, stream>>>(xcur_f, nullptr, h2, mlpb + (size_t)l * 256,
                                                 lng + (size_t)(l * 3 + 2) * 256,
                                                 lnb + (size_t)(l * 3 + 2) * 256,
                                                 last ? out : xbf, last ? nullptr : xbb);
        xcur_f = xbf; ++step;
    }
}

// Round 4
// 1329.086 us; speedup vs baseline: 2.9067x; 2.9067x over previous
//
#include <hip/hip_runtime.h>
#include <hip/hip_bf16.h>

#define N_NODES 10000
#define N_EDGES 40000
#define NLAYERS 5

typedef __bf16 bf16x8 __attribute__((ext_vector_type(8)));
typedef __bf16 bf16x4 __attribute__((ext_vector_type(4)));
typedef float  f32x4  __attribute__((ext_vector_type(4)));

__device__ __forceinline__ bf16x8 cvt8(float4 a, float4 b) {
    bf16x8 r;
    r[0] = (__bf16)a.x; r[1] = (__bf16)a.y; r[2] = (__bf16)a.z; r[3] = (__bf16)a.w;
    r[4] = (__bf16)b.x; r[5] = (__bf16)b.y; r[6] = (__bf16)b.z; r[7] = (__bf16)b.w;
    return r;
}

__device__ __forceinline__ void gload_lds16(const void* g, void* l) {
    __builtin_amdgcn_global_load_lds(
        (const __attribute__((address_space(1))) void*)g,
        (__attribute__((address_space(3))) void*)l, 16, 0, 0);
}

// ---------------- f32 -> bf16 conversion (8 elems/thread) ----------------
__global__ __launch_bounds__(256) void cvt_chunks(
    const float* __restrict__ s, __bf16* __restrict__ d,
    long chunk, long dstStride, long total8)
{
    for (long i = (long)blockIdx.x * blockDim.x + threadIdx.x; i < total8;
         i += (long)gridDim.x * blockDim.x) {
        long e = i * 8;
        long ch = e / chunk;
        long r  = e - ch * chunk;
        float4 a = *(const float4*)(s + e);
        float4 b = *(const float4*)(s + e + 4);
        *(bf16x8*)(d + ch * dstStride + r) = cvt8(a, b);
    }
}

// ---------------- CSR build (once per call) ----------------
__global__ __launch_bounds__(256) void hist_dst(
    const int* __restrict__ eidx, int* __restrict__ counts)
{
    int e = blockIdx.x * 256 + threadIdx.x;
    if (e < N_EDGES) atomicAdd(&counts[eidx[N_EDGES + e]], 1);
}

// single-block exclusive scan of counts[0..n) -> offs[0..n], wrk copy
__global__ __launch_bounds__(256) void scan_offsets(
    const int* __restrict__ counts, int* __restrict__ offs,
    int* __restrict__ wrk, int n)
{
    __shared__ int sm[256];
    __shared__ int carry;
    const int tid = threadIdx.x;
    if (tid == 0) carry = 0;
    __syncthreads();
    for (int base = 0; base < n; base += 256) {
        int i = base + tid;
        int v = (i < n) ? counts[i] : 0;
        sm[tid] = v;
        __syncthreads();
        for (int off = 1; off < 256; off <<= 1) {
            int t = (tid >= off) ? sm[tid - off] : 0;
            __syncthreads();
            sm[tid] += t;
            __syncthreads();
        }
        int incl = sm[tid];
        int excl = incl - v + carry;
        if (i < n) { offs[i] = excl; wrk[i] = excl; }
        __syncthreads();
        if (tid == 255) carry += incl;
        __syncthreads();
    }
    if (tid == 0) offs[n] = carry;
}

__global__ __launch_bounds__(256) void scatter_csr(
    const int* __restrict__ eidx, int* __restrict__ wrk, int* __restrict__ csr_eid)
{
    int e = blockIdx.x * 256 + threadIdx.x;
    if (e < N_EDGES) {
        int d = eidx[N_EDGES + e];
        int pos = atomicAdd(&wrk[d], 1);
        csr_eid[pos] = e;
    }
}

// ---------------- LDS-staged bf16 GEMM: C = A[MxK] @ W[NcxK]^T ----------------
// tile 128x64, BK=64, 256 threads (4 waves, 2x2), XOR-swizzled LDS (both sides).
// MODE 0: f32 out. MODE 1: bf16 out. MODE 2: bf16 out with QKV transpose remap
//   (cols 0..511 -> Q^T [a][h], 512..1023 -> K^T [a][h], 1024..1535 -> V [h][a]).
template<int MODE>
__global__ __launch_bounds__(256) void gemm_lds(
    const __bf16* __restrict__ A, const __bf16* __restrict__ W,
    float* __restrict__ Cf, __bf16* __restrict__ Ch,
    int M, int K, int ldc, int coloff)
{
    __shared__ __bf16 As[128 * 64];   // 16 KB
    __shared__ __bf16 Wsh[64 * 64];   // 8 KB
    const int tid = threadIdx.x;
    const int ln  = tid & 63;
    const int wv  = tid >> 6;
    const int wr  = wv >> 1, wc = wv & 1;
    const int brow0 = blockIdx.x * 128;
    const int colb0 = blockIdx.y * 64;

    const int srow = ln >> 3;
    const int scol = ((ln & 7) ^ srow) * 8;

    const int fr = ln & 15;
    const int kq = ln >> 4;
    char* asb = (char*)As;
    char* wsb = (char*)Wsh;

    f32x4 acc[4][2];
    #pragma unroll
    for (int m = 0; m < 4; ++m)
        #pragma unroll
        for (int n = 0; n < 2; ++n) acc[m][n] = (f32x4){0.f, 0.f, 0.f, 0.f};

    const int nt = K >> 6;
    for (int t = 0; t < nt; ++t) {
        const int kk0 = t << 6;
        if (t) __syncthreads();
        #pragma unroll
        for (int c = 0; c < 4; ++c) {
            int ch = wv * 4 + c;
            int grow = brow0 + ch * 8 + srow;
            if (grow >= M) grow = M - 1;
            gload_lds16(A + (size_t)grow * K + kk0 + scol, asb + ch * 1024);
        }
        #pragma unroll
        for (int c = 0; c < 2; ++c) {
            int ch = wv * 2 + c;
            int grow = colb0 + ch * 8 + srow;
            gload_lds16(W + (size_t)grow * K + kk0 + scol, wsb + ch * 1024);
        }
        __syncthreads();
        #pragma unroll
        for (int ks = 0; ks < 2; ++ks) {
            const int kb = ks * 64 + kq * 16;
            const int sw = (fr & 7) << 4;
            bf16x8 af[4], wf[2];
            #pragma unroll
            for (int m = 0; m < 4; ++m) {
                int row = wr * 64 + m * 16 + fr;
                af[m] = *(const bf16x8*)(asb + row * 128 + (kb ^ sw));
            }
            #pragma unroll
            for (int n = 0; n < 2; ++n) {
                int row = wc * 32 + n * 16 + fr;
                wf[n] = *(const bf16x8*)(wsb + row * 128 + (kb ^ sw));
            }
            #pragma unroll
            for (int m = 0; m < 4; ++m)
                #pragma unroll
                for (int n = 0; n < 2; ++n)
                    acc[m][n] = __builtin_amdgcn_mfma_f32_16x16x32_bf16(
                        af[m], wf[n], acc[m][n], 0, 0, 0);
        }
    }

    int ocol[2];
    #pragma unroll
    for (int n = 0; n < 2; ++n) {
        int c = coloff + colb0 + wc * 32 + fr + n * 16;
        if (MODE == 2) {
            if (c < 512)        c = ((c & 15) << 5) | (c >> 4);
            else if (c < 1024)  { int c2 = c - 512; c = 512 + (((c2 & 15) << 5) | (c2 >> 4)); }
        }
        ocol[n] = c;
    }

    const int rq = (ln >> 4) * 4;
    #pragma unroll
    for (int m = 0; m < 4; ++m) {
        #pragma unroll
        for (int rr = 0; rr < 4; ++rr) {
            int orow = brow0 + wr * 64 + m * 16 + rq + rr;
            if (orow < M) {
                size_t base = (size_t)orow * ldc;
                #pragma unroll
                for (int n = 0; n < 2; ++n) {
                    if (MODE == 0) Cf[base + ocol[n]] = acc[m][n][rr];
                    else           Ch[base + ocol[n]] = (__bf16)acc[m][n][rr];
                }
            }
        }
    }
}

// ---------------- per-dst attention via MFMA, one wave per node ----------------
// qkv layout per node (1536 bf16): Q^T[16a][32h] | K^T[16a][32h] | V[32h][16b].
// For each incoming edge: alphaT = mfma(K,Q); softmax over b; PV accumulated
// into MFMA C across edges. Single coalesced bf16 row write, no atomics.
__global__ __launch_bounds__(256) void edge_attn_csr(
    const int* __restrict__ csr_off, const int* __restrict__ csr_eid,
    const int* __restrict__ eidx, const __bf16* __restrict__ qkv,
    __bf16* __restrict__ attn_bf)
{
    const int lane = threadIdx.x & 63;
    const int d = blockIdx.x * 4 + (threadIdx.x >> 6);
    const int fr = lane & 15;
    const int G  = lane >> 4;

    const __bf16* qT = qkv + (size_t)d * 1536;
    const bf16x8 qf = *(const bf16x8*)(qT + fr * 32 + G * 8);

    const f32x4 zero = {0.f, 0.f, 0.f, 0.f};
    f32x4 acc0 = zero, acc1 = zero;

    const int i0 = csr_off[d], i1 = csr_off[d + 1];
    for (int i = i0; i < i1; ++i) {
        const int e = csr_eid[i];
        const int s = eidx[e];
        const __bf16* kT = qkv + (size_t)s * 1536 + 512;
        const __bf16* vp = qkv + (size_t)s * 1536 + 1024;

        bf16x8 kf = *(const bf16x8*)(kT + fr * 32 + G * 8);
        f32x4 al = __builtin_amdgcn_mfma_f32_16x16x32_bf16(kf, qf, zero, 0, 0, 0);
        // lane holds alphaT[b = G*4+r][a = fr]

        float mx = fmaxf(fmaxf(al[0], al[1]), fmaxf(al[2], al[3]));
        mx = fmaxf(mx, __shfl_xor(mx, 16));
        mx = fmaxf(mx, __shfl_xor(mx, 32));
        float p[4];
        #pragma unroll
        for (int r = 0; r < 4; ++r) p[r] = __expf((al[r] - mx) * 0.25f);
        float sum = p[0] + p[1] + p[2] + p[3];
        sum += __shfl_xor(sum, 16);
        sum += __shfl_xor(sum, 32);
        const float inv = 1.f / sum;

        // PV A-fragment: lane needs att[a=fr][b = G*8+j] (G<2), else 0.
        bf16x8 paf;
        #pragma unroll
        for (int j = 0; j < 8; ++j) {
            int srcLane = fr + ((G * 8 + j) >> 2) * 16;
            float v = __shfl(p[j & 3], srcLane);
            paf[j] = (G < 2) ? (__bf16)(v * inv) : (__bf16)0.f;
        }

        bf16x8 vf0 = {0, 0, 0, 0, 0, 0, 0, 0};
        bf16x8 vf1 = {0, 0, 0, 0, 0, 0, 0, 0};
        if (G < 2) {
            vf0 = *(const bf16x8*)(vp + fr * 16 + G * 8);
            vf1 = *(const bf16x8*)(vp + (16 + fr) * 16 + G * 8);
        }
        acc0 = __builtin_amdgcn_mfma_f32_16x16x32_bf16(paf, vf0, acc0, 0, 0, 0);
        acc1 = __builtin_amdgcn_mfma_f32_16x16x32_bf16(paf, vf1, acc1, 0, 0, 0);
    }

    // lane holds msg[a = G*4+r][h = hb*16+fr]; attn[d][h*16+a], coalesced bf16x4.
    __bf16* ob = attn_bf + (size_t)d * 512;
    bf16x4 o0, o1;
    #pragma unroll
    for (int r = 0; r < 4; ++r) { o0[r] = (__bf16)acc0[r]; o1[r] = (__bf16)acc1[r]; }
    *(bf16x4*)(ob + fr * 16 + G * 4)         = o0;
    *(bf16x4*)(ob + 256 + fr * 16 + G * 4)   = o1;
}

// ---------------- fused residual + LayerNorm ----------------
__global__ __launch_bounds__(256) void ln_fused(
    const float* __restrict__ x, const __bf16* __restrict__ tb,
    const float* __restrict__ tf, const float* __restrict__ bias,
    const float* __restrict__ g, const float* __restrict__ b,
    float* __restrict__ outf, __bf16* __restrict__ outb)
{
    int wv = threadIdx.x >> 6;
    int lane = threadIdx.x & 63;
    int row = blockIdx.x * 4 + wv;
    int c = lane * 4;
    size_t off = (size_t)row * 256 + c;

    float4 v = *(const float4*)(x + off);
    float4 u = *(const float4*)(tf + off);
    v.x += u.x; v.y += u.y; v.z += u.z; v.w += u.w;
    if (tb) {
        bf16x4 w = *(const bf16x4*)(tb + off);
        v.x += (float)w[0]; v.y += (float)w[1]; v.z += (float)w[2]; v.w += (float)w[3];
    }
    float4 bi = *(const float4*)(bias + c);
    v.x += bi.x; v.y += bi.y; v.z += bi.z; v.w += bi.w;

    float sum = v.x + v.y + v.z + v.w;
    float sq  = v.x*v.x + v.y*v.y + v.z*v.z + v.w*v.w;
    #pragma unroll
    for (int m = 1; m < 64; m <<= 1) {
        sum += __shfl_xor(sum, m);
        sq  += __shfl_xor(sq,  m);
    }
    float mean = sum * (1.f / 256.f);
    float var  = sq * (1.f / 256.f) - mean * mean;
    float invs = rsqrtf(var + 1e-5f);

    float4 gg = *(const float4*)(g + c);
    float4 bb = *(const float4*)(b + c);
    float4 o;
    o.x = (v.x - mean) * invs * gg.x + bb.x;
    o.y = (v.y - mean) * invs * gg.y + bb.y;
    o.z = (v.z - mean) * invs * gg.z + bb.z;
    o.w = (v.w - mean) * invs * gg.w + bb.w;
    *(float4*)(outf + off) = o;
    if (outb) {
        bf16x4 ob;
        ob[0] = (__bf16)o.x; ob[1] = (__bf16)o.y;
        ob[2] = (__bf16)o.z; ob[3] = (__bf16)o.w;
        *(bf16x4*)(outb + off) = ob;
    }
}

extern "C" void kernel_launch(void* const* d_in, const int* in_sizes, int n_in,
                              void* d_out, int out_size, void* d_ws, size_t ws_size,
                              hipStream_t stream)
{
    const int*   eidx = (const int*)  d_in[0];
    const float* x_in = (const float*)d_in[1];
    const float* We   = (const float*)d_in[2];
    const float* Wq   = (const float*)d_in[3];
    const float* Wk   = (const float*)d_in[4];
    const float* Wv   = (const float*)d_in[5];
    const float* Wo   = (const float*)d_in[6];
    const float* bo   = (const float*)d_in[7];
    const float* lng  = (const float*)d_in[8];
    const float* lnb  = (const float*)d_in[9];
    const float* mlpW = (const float*)d_in[10];
    const float* mlpb = (const float*)d_in[11];
    float* out = (float*)d_out;

    char* p = (char*)d_ws;
    __bf16* wE   = (__bf16*)p; p += (size_t)10 * 65536  * 2;
    __bf16* wQKV = (__bf16*)p; p += (size_t)10 * 393216 * 2;
    __bf16* wO   = (__bf16*)p; p += (size_t)10 * 131072 * 2;
    __bf16* wM   = (__bf16*)p; p += (size_t)5  * 65536  * 2;
    __bf16* qkv  = (__bf16*)p; p += (size_t)N_NODES * 1536 * 2;
    __bf16* attn_bf = (__bf16*)p; p += (size_t)N_NODES * 512 * 2;
    __bf16* xeb  = (__bf16*)p; p += (size_t)N_NODES * 256 * 2;
    float*  xbf  = (float*) p; p += (size_t)N_NODES * 256 * 4;
    __bf16* xbb  = (__bf16*)p; p += (size_t)N_NODES * 256 * 2;
    int* counts  = (int*)p;    p += (size_t)(N_NODES + 16) * 4;
    int* csr_off = (int*)p;    p += (size_t)(N_NODES + 16) * 4;
    int* csr_wrk = (int*)p;    p += (size_t)(N_NODES + 16) * 4;
    int* csr_eid = (int*)p;    p += (size_t)N_EDGES * 4;
    if ((size_t)(p - (char*)d_ws) > ws_size) return;
    float* h2 = (float*)qkv;   // alias: qkv dead when h2 (Wo/MLP out) is written

    dim3 blk(256);
    auto cvtg = [](long total8) { long g = (total8 + 255) / 256; return dim3((unsigned)(g > 2048 ? 2048 : g)); };

    // ---- once per call: CSR build + weights/x to bf16 ----
    hipMemsetAsync(counts, 0, (size_t)(N_NODES + 16) * 4, stream);
    hist_dst<<<dim3(157), blk, 0, stream>>>(eidx, counts);
    scan_offsets<<<dim3(1), blk, 0, stream>>>(counts, csr_off, csr_wrk, N_NODES);
    scatter_csr<<<dim3(157), blk, 0, stream>>>(eidx, csr_wrk, csr_eid);

    cvt_chunks<<<cvtg(81920), blk, 0, stream>>>(We,   wE,            65536,  65536, 81920);
    cvt_chunks<<<cvtg(163840), blk, 0, stream>>>(Wq,  wQKV,          131072, 393216, 163840);
    cvt_chunks<<<cvtg(163840), blk, 0, stream>>>(Wk,  wQKV + 131072, 131072, 393216, 163840);
    cvt_chunks<<<cvtg(163840), blk, 0, stream>>>(Wv,  wQKV + 262144, 131072, 393216, 163840);
    cvt_chunks<<<cvtg(163840), blk, 0, stream>>>(Wo,  wO,            131072, 131072, 163840);
    cvt_chunks<<<cvtg(40960), blk, 0, stream>>>(mlpW, wM,            65536,  65536, 40960);
    cvt_chunks<<<cvtg(320000), blk, 0, stream>>>(x_in, xbb,          2560000, 2560000, 320000);

    dim3 gN256(79, 4);
    dim3 gQKV(79, 24);

    const float* xcur_f = x_in;
    int step = 0;
    for (int l = 0; l < NLAYERS; ++l) {
        for (int s = 0; s < 2; ++s) {
            size_t ls = (size_t)(l * 2 + s);
            gemm_lds<1><<<gN256, blk, 0, stream>>>(xbb, wE + ls * 65536, nullptr, xeb,
                                                   N_NODES, 256, 256, 0);
            gemm_lds<2><<<gQKV, blk, 0, stream>>>(xeb, wQKV + ls * 393216, nullptr, qkv,
                                                  N_NODES, 256, 1536, 0);
            edge_attn_csr<<<dim3(N_NODES / 4), blk, 0, stream>>>(csr_off, csr_eid, eidx,
                                                                 qkv, attn_bf);
            gemm_lds<0><<<gN256, blk, 0, stream>>>(attn_bf, wO + ls * 131072, h2, nullptr,
                                                   N_NODES, 512, 256, 0);
            bool last = (step == 14);
            ln_fused<<<dim3(2500), blk, 0, stream>>>(xcur_f, xeb, h2, bo + ls * 256,
                                                     lng + (size_t)(l * 3 + s) * 256,
                                                     lnb + (size_t)(l * 3 + s) * 256,
                                                     last ? out : xbf, last ? nullptr : xbb);
            xcur_f = xbf; ++step;
        }
        gemm_lds<0><<<gN256, blk, 0, stream>>>(xbb, wM + (size_t)l * 65536, h2, nullptr,
                                               N_NODES, 256, 256, 0);
        bool last = (step == 14);
        ln_fused<<<dim3(2500), blk, 0, stream>>>(xcur_f, nullptr, h2, mlpb + (size_t)l * 256,
                                                 lng + (size_t)(l * 3 + 2) * 256,
                                                 lnb + (size_t)(l * 3 + 2) * 256,
                                                 last ? out : xbf, last ? nullptr : xbb);
        xcur_f = xbf; ++step;
    }
}

// Round 5
// 828.327 us; speedup vs baseline: 4.6640x; 1.6045x over previous
//
#include <hip/hip_runtime.h>
#include <hip/hip_bf16.h>

#define N_NODES 10000
#define N_EDGES 40000
#define NLAYERS 5

typedef __bf16 bf16x8 __attribute__((ext_vector_type(8)));
typedef __bf16 bf16x4 __attribute__((ext_vector_type(4)));
typedef float  f32x4  __attribute__((ext_vector_type(4)));

__device__ __forceinline__ bf16x8 cvt8(float4 a, float4 b) {
    bf16x8 r;
    r[0] = (__bf16)a.x; r[1] = (__bf16)a.y; r[2] = (__bf16)a.z; r[3] = (__bf16)a.w;
    r[4] = (__bf16)b.x; r[5] = (__bf16)b.y; r[6] = (__bf16)b.z; r[7] = (__bf16)b.w;
    return r;
}

__device__ __forceinline__ void gload_lds16(const void* g, void* l) {
    __builtin_amdgcn_global_load_lds(
        (const __attribute__((address_space(1))) void*)g,
        (__attribute__((address_space(3))) void*)l, 16, 0, 0);
}

// ---------------- f32 -> bf16 conversion (8 elems/thread) ----------------
__global__ __launch_bounds__(256) void cvt_chunks(
    const float* __restrict__ s, __bf16* __restrict__ d,
    long chunk, long dstStride, long total8)
{
    for (long i = (long)blockIdx.x * blockDim.x + threadIdx.x; i < total8;
         i += (long)gridDim.x * blockDim.x) {
        long e = i * 8;
        long ch = e / chunk;
        long r  = e - ch * chunk;
        float4 a = *(const float4*)(s + e);
        float4 b = *(const float4*)(s + e + 4);
        *(bf16x8*)(d + ch * dstStride + r) = cvt8(a, b);
    }
}

// Wq/Wk rows permuted so the GEMM's natural (coalesced) column order directly
// produces Q^T[a][h]: dst row m <- src row (m&31)*16 + (m>>5).
// S: [10][512][256] f32.  D: section base (Q at +0, K at +512*256) with
// per-slot stride 393216.  total8 = 10*512*256/8.
__global__ __launch_bounds__(256) void cvt_perm_qk(
    const float* __restrict__ S, __bf16* __restrict__ D, long total8)
{
    for (long i = (long)blockIdx.x * blockDim.x + threadIdx.x; i < total8;
         i += (long)gridDim.x * blockDim.x) {
        long e = i * 8;
        int slot = (int)(e >> 17);           // /131072
        int rem  = (int)(e & 131071);
        int row  = rem >> 8;
        int col  = rem & 255;
        int srow = ((row & 31) << 4) | (row >> 5);
        const float* sp = S + ((long)slot << 17) + ((long)srow << 8) + col;
        float4 a = *(const float4*)sp;
        float4 b = *(const float4*)(sp + 4);
        *(bf16x8*)(D + (long)slot * 393216 + ((long)row << 8) + col) = cvt8(a, b);
    }
}

// ---------------- CSR build (once per call) ----------------
__global__ __launch_bounds__(256) void hist_dst(
    const int* __restrict__ eidx, int* __restrict__ counts)
{
    int e = blockIdx.x * 256 + threadIdx.x;
    if (e < N_EDGES) atomicAdd(&counts[eidx[N_EDGES + e]], 1);
}

// single-block 2-level exclusive scan: thread t owns elements [t*40,(t+1)*40)
__global__ __launch_bounds__(256) void scan_offsets(
    const int* __restrict__ counts, int* __restrict__ offs,
    int* __restrict__ wrk, int n)
{
    const int tid = threadIdx.x;
    const int base = tid * 40;
    int local[40];
    int s = 0;
    #pragma unroll
    for (int j = 0; j < 40; ++j) {
        int i = base + j;
        int v = (i < n) ? counts[i] : 0;
        local[j] = s; s += v;
    }
    __shared__ int sm[256];
    sm[tid] = s;
    __syncthreads();
    for (int off = 1; off < 256; off <<= 1) {
        int t2 = (tid >= off) ? sm[tid - off] : 0;
        __syncthreads();
        sm[tid] += t2;
        __syncthreads();
    }
    int pre = (tid == 0) ? 0 : sm[tid - 1];
    #pragma unroll
    for (int j = 0; j < 40; ++j) {
        int i = base + j;
        if (i < n) { int v = pre + local[j]; offs[i] = v; wrk[i] = v; }
    }
    if (tid == 255) offs[n] = sm[255];
}

__global__ __launch_bounds__(256) void scatter_csr(
    const int* __restrict__ eidx, int* __restrict__ wrk, int* __restrict__ csr_eid)
{
    int e = blockIdx.x * 256 + threadIdx.x;
    if (e < N_EDGES) {
        int d = eidx[N_EDGES + e];
        int pos = atomicAdd(&wrk[d], 1);
        csr_eid[pos] = e;
    }
}

// ---------------- LDS-staged bf16 GEMM: C = A[MxK] @ W[NcxK]^T ----------------
// tile 128xBN, BK=64, 256 threads (4 waves, 2x2), XOR-swizzled LDS.
// blockIdx.x = column block (consecutive blocks share the A row panel),
// blockIdx.y = row block.  MODE 0: f32 out. MODE 1: bf16 out.
template<int MODE, int BN>
__global__ __launch_bounds__(256) void gemm_lds(
    const __bf16* __restrict__ A, const __bf16* __restrict__ W,
    float* __restrict__ Cf, __bf16* __restrict__ Ch,
    int M, int K, int ldc, int coloff)
{
    __shared__ __bf16 As[128 * 64];
    __shared__ __bf16 Wsh[BN * 64];
    constexpr int NF = BN / 32;            // col fragments per wave
    const int tid = threadIdx.x;
    const int ln  = tid & 63;
    const int wv  = tid >> 6;
    const int wr  = wv >> 1, wc = wv & 1;
    const int brow0 = blockIdx.y * 128;
    const int colb0 = blockIdx.x * BN;

    const int srow = ln >> 3;
    const int scol = ((ln & 7) ^ srow) * 8;

    const int fr = ln & 15;
    const int kq = ln >> 4;
    char* asb = (char*)As;
    char* wsb = (char*)Wsh;

    f32x4 acc[4][NF];
    #pragma unroll
    for (int m = 0; m < 4; ++m)
        #pragma unroll
        for (int n = 0; n < NF; ++n) acc[m][n] = (f32x4){0.f, 0.f, 0.f, 0.f};

    const int nt = K >> 6;
    for (int t = 0; t < nt; ++t) {
        const int kk0 = t << 6;
        if (t) __syncthreads();
        #pragma unroll
        for (int c = 0; c < 4; ++c) {
            int ch = wv * 4 + c;
            int grow = brow0 + ch * 8 + srow;
            if (grow >= M) grow = M - 1;
            gload_lds16(A + (size_t)grow * K + kk0 + scol, asb + ch * 1024);
        }
        #pragma unroll
        for (int c = 0; c < NF; ++c) {
            int ch = wv * NF + c;
            int grow = colb0 + ch * 8 + srow;
            gload_lds16(W + (size_t)grow * K + kk0 + scol, wsb + ch * 1024);
        }
        __syncthreads();
        #pragma unroll
        for (int ks = 0; ks < 2; ++ks) {
            const int kb = ks * 64 + kq * 16;
            const int sw = (fr & 7) << 4;
            bf16x8 af[4], wf[NF];
            #pragma unroll
            for (int m = 0; m < 4; ++m) {
                int row = wr * 64 + m * 16 + fr;
                af[m] = *(const bf16x8*)(asb + row * 128 + (kb ^ sw));
            }
            #pragma unroll
            for (int n = 0; n < NF; ++n) {
                int row = wc * (BN / 2) + n * 16 + fr;
                wf[n] = *(const bf16x8*)(wsb + row * 128 + (kb ^ sw));
            }
            #pragma unroll
            for (int m = 0; m < 4; ++m)
                #pragma unroll
                for (int n = 0; n < NF; ++n)
                    acc[m][n] = __builtin_amdgcn_mfma_f32_16x16x32_bf16(
                        af[m], wf[n], acc[m][n], 0, 0, 0);
        }
    }

    const int rq = (ln >> 4) * 4;
    #pragma unroll
    for (int m = 0; m < 4; ++m) {
        #pragma unroll
        for (int rr = 0; rr < 4; ++rr) {
            int orow = brow0 + wr * 64 + m * 16 + rq + rr;
            if (orow < M) {
                size_t base = (size_t)orow * ldc + coloff + colb0 + wc * (BN / 2) + fr;
                #pragma unroll
                for (int n = 0; n < NF; ++n) {
                    if (MODE == 0) Cf[base + n * 16] = acc[m][n][rr];
                    else           Ch[base + n * 16] = (__bf16)acc[m][n][rr];
                }
            }
        }
    }
}

// ---------------- per-dst attention via MFMA, one wave per node ----------------
// qkv layout per node (1536 bf16): Q^T[16a][32h] | K^T[16a][32h] | V[32h][16b].
__global__ __launch_bounds__(256) void edge_attn_csr(
    const int* __restrict__ csr_off, const int* __restrict__ csr_eid,
    const int* __restrict__ eidx, const __bf16* __restrict__ qkv,
    __bf16* __restrict__ attn_bf)
{
    const int lane = threadIdx.x & 63;
    const int d = blockIdx.x * 4 + (threadIdx.x >> 6);
    const int fr = lane & 15;
    const int G  = lane >> 4;

    const __bf16* qT = qkv + (size_t)d * 1536;
    const bf16x8 qf = *(const bf16x8*)(qT + fr * 32 + G * 8);

    const f32x4 zero = {0.f, 0.f, 0.f, 0.f};
    f32x4 acc0 = zero, acc1 = zero;

    const int i0 = csr_off[d], i1 = csr_off[d + 1];
    for (int i = i0; i < i1; ++i) {
        const int e = csr_eid[i];
        const int s = eidx[e];
        const __bf16* kT = qkv + (size_t)s * 1536 + 512;
        const __bf16* vp = qkv + (size_t)s * 1536 + 1024;

        bf16x8 kf = *(const bf16x8*)(kT + fr * 32 + G * 8);
        f32x4 al = __builtin_amdgcn_mfma_f32_16x16x32_bf16(kf, qf, zero, 0, 0, 0);

        float mx = fmaxf(fmaxf(al[0], al[1]), fmaxf(al[2], al[3]));
        mx = fmaxf(mx, __shfl_xor(mx, 16));
        mx = fmaxf(mx, __shfl_xor(mx, 32));
        float p[4];
        #pragma unroll
        for (int r = 0; r < 4; ++r) p[r] = __expf((al[r] - mx) * 0.25f);
        float sum = p[0] + p[1] + p[2] + p[3];
        sum += __shfl_xor(sum, 16);
        sum += __shfl_xor(sum, 32);
        const float inv = 1.f / sum;

        bf16x8 paf;
        #pragma unroll
        for (int j = 0; j < 8; ++j) {
            int srcLane = fr + ((G * 8 + j) >> 2) * 16;
            float v = __shfl(p[j & 3], srcLane);
            paf[j] = (G < 2) ? (__bf16)(v * inv) : (__bf16)0.f;
        }

        bf16x8 vf0 = {0, 0, 0, 0, 0, 0, 0, 0};
        bf16x8 vf1 = {0, 0, 0, 0, 0, 0, 0, 0};
        if (G < 2) {
            vf0 = *(const bf16x8*)(vp + fr * 16 + G * 8);
            vf1 = *(const bf16x8*)(vp + (16 + fr) * 16 + G * 8);
        }
        acc0 = __builtin_amdgcn_mfma_f32_16x16x32_bf16(paf, vf0, acc0, 0, 0, 0);
        acc1 = __builtin_amdgcn_mfma_f32_16x16x32_bf16(paf, vf1, acc1, 0, 0, 0);
    }

    __bf16* ob = attn_bf + (size_t)d * 512;
    bf16x4 o0, o1;
    #pragma unroll
    for (int r = 0; r < 4; ++r) { o0[r] = (__bf16)acc0[r]; o1[r] = (__bf16)acc1[r]; }
    *(bf16x4*)(ob + fr * 16 + G * 4)       = o0;
    *(bf16x4*)(ob + 256 + fr * 16 + G * 4) = o1;
}

// ---------------- fused residual + LayerNorm ----------------
__global__ __launch_bounds__(256) void ln_fused(
    const float* __restrict__ x, const __bf16* __restrict__ tb,
    const float* __restrict__ tf, const float* __restrict__ bias,
    const float* __restrict__ g, const float* __restrict__ b,
    float* __restrict__ outf, __bf16* __restrict__ outb)
{
    int wv = threadIdx.x >> 6;
    int lane = threadIdx.x & 63;
    int row = blockIdx.x * 4 + wv;
    int c = lane * 4;
    size_t off = (size_t)row * 256 + c;

    float4 v = *(const float4*)(x + off);
    float4 u = *(const float4*)(tf + off);
    v.x += u.x; v.y += u.y; v.z += u.z; v.w += u.w;
    if (tb) {
        bf16x4 w = *(const bf16x4*)(tb + off);
        v.x += (float)w[0]; v.y += (float)w[1]; v.z += (float)w[2]; v.w += (float)w[3];
    }
    float4 bi = *(const float4*)(bias + c);
    v.x += bi.x; v.y += bi.y; v.z += bi.z; v.w += bi.w;

    float sum = v.x + v.y + v.z + v.w;
    float sq  = v.x*v.x + v.y*v.y + v.z*v.z + v.w*v.w;
    #pragma unroll
    for (int m = 1; m < 64; m <<= 1) {
        sum += __shfl_xor(sum, m);
        sq  += __shfl_xor(sq,  m);
    }
    float mean = sum * (1.f / 256.f);
    float var  = sq * (1.f / 256.f) - mean * mean;
    float invs = rsqrtf(var + 1e-5f);

    float4 gg = *(const float4*)(g + c);
    float4 bb = *(const float4*)(b + c);
    float4 o;
    o.x = (v.x - mean) * invs * gg.x + bb.x;
    o.y = (v.y - mean) * invs * gg.y + bb.y;
    o.z = (v.z - mean) * invs * gg.z + bb.z;
    o.w = (v.w - mean) * invs * gg.w + bb.w;
    *(float4*)(outf + off) = o;
    if (outb) {
        bf16x4 ob;
        ob[0] = (__bf16)o.x; ob[1] = (__bf16)o.y;
        ob[2] = (__bf16)o.z; ob[3] = (__bf16)o.w;
        *(bf16x4*)(outb + off) = ob;
    }
}

extern "C" void kernel_launch(void* const* d_in, const int* in_sizes, int n_in,
                              void* d_out, int out_size, void* d_ws, size_t ws_size,
                              hipStream_t stream)
{
    const int*   eidx = (const int*)  d_in[0];
    const float* x_in = (const float*)d_in[1];
    const float* We   = (const float*)d_in[2];
    const float* Wq   = (const float*)d_in[3];
    const float* Wk   = (const float*)d_in[4];
    const float* Wv   = (const float*)d_in[5];
    const float* Wo   = (const float*)d_in[6];
    const float* bo   = (const float*)d_in[7];
    const float* lng  = (const float*)d_in[8];
    const float* lnb  = (const float*)d_in[9];
    const float* mlpW = (const float*)d_in[10];
    const float* mlpb = (const float*)d_in[11];
    float* out = (float*)d_out;

    char* p = (char*)d_ws;
    __bf16* wE   = (__bf16*)p; p += (size_t)10 * 65536  * 2;
    __bf16* wQKV = (__bf16*)p; p += (size_t)10 * 393216 * 2;
    __bf16* wO   = (__bf16*)p; p += (size_t)10 * 131072 * 2;
    __bf16* wM   = (__bf16*)p; p += (size_t)5  * 65536  * 2;
    __bf16* qkv  = (__bf16*)p; p += (size_t)N_NODES * 1536 * 2;
    __bf16* attn_bf = (__bf16*)p; p += (size_t)N_NODES * 512 * 2;
    __bf16* xeb  = (__bf16*)p; p += (size_t)N_NODES * 256 * 2;
    float*  xbf  = (float*) p; p += (size_t)N_NODES * 256 * 4;
    __bf16* xbb  = (__bf16*)p; p += (size_t)N_NODES * 256 * 2;
    int* counts  = (int*)p;    p += (size_t)(N_NODES + 16) * 4;
    int* csr_off = (int*)p;    p += (size_t)(N_NODES + 16) * 4;
    int* csr_wrk = (int*)p;    p += (size_t)(N_NODES + 16) * 4;
    int* csr_eid = (int*)p;    p += (size_t)N_EDGES * 4;
    if ((size_t)(p - (char*)d_ws) > ws_size) return;
    float* h2 = (float*)qkv;   // alias: qkv dead when h2 (Wo/MLP out) is written

    dim3 blk(256);
    auto cvtg = [](long total8) { long g = (total8 + 255) / 256; return dim3((unsigned)(g > 2048 ? 2048 : g)); };

    // ---- once per call: CSR build + weights/x to bf16 ----
    hipMemsetAsync(counts, 0, (size_t)(N_NODES + 16) * 4, stream);
    hist_dst<<<dim3(157), blk, 0, stream>>>(eidx, counts);
    scan_offsets<<<dim3(1), blk, 0, stream>>>(counts, csr_off, csr_wrk, N_NODES);
    scatter_csr<<<dim3(157), blk, 0, stream>>>(eidx, csr_wrk, csr_eid);

    cvt_chunks<<<cvtg(81920), blk, 0, stream>>>(We,   wE, 65536, 65536, 81920);
    cvt_perm_qk<<<cvtg(163840), blk, 0, stream>>>(Wq, wQKV,          163840);
    cvt_perm_qk<<<cvtg(163840), blk, 0, stream>>>(Wk, wQKV + 131072, 163840);
    cvt_chunks<<<cvtg(163840), blk, 0, stream>>>(Wv,  wQKV + 262144, 131072, 393216, 163840);
    cvt_chunks<<<cvtg(163840), blk, 0, stream>>>(Wo,  wO, 131072, 131072, 163840);
    cvt_chunks<<<cvtg(40960), blk, 0, stream>>>(mlpW, wM, 65536, 65536, 40960);
    cvt_chunks<<<cvtg(320000), blk, 0, stream>>>(x_in, xbb, 2560000, 2560000, 320000);

    dim3 gN256(4, 79);     // BN=64,  Nc=256
    dim3 gQKV(12, 79);     // BN=128, Nc=1536

    const float* xcur_f = x_in;
    int step = 0;
    for (int l = 0; l < NLAYERS; ++l) {
        for (int s = 0; s < 2; ++s) {
            size_t ls = (size_t)(l * 2 + s);
            gemm_lds<1, 64><<<gN256, blk, 0, stream>>>(xbb, wE + ls * 65536, nullptr, xeb,
                                                       N_NODES, 256, 256, 0);
            gemm_lds<1, 128><<<gQKV, blk, 0, stream>>>(xeb, wQKV + ls * 393216, nullptr, qkv,
                                                       N_NODES, 256, 1536, 0);
            edge_attn_csr<<<dim3(N_NODES / 4), blk, 0, stream>>>(csr_off, csr_eid, eidx,
                                                                 qkv, attn_bf);
            gemm_lds<0, 64><<<gN256, blk, 0, stream>>>(attn_bf, wO + ls * 131072, h2, nullptr,
                                                       N_NODES, 512, 256, 0);
            bool last = (step == 14);
            ln_fused<<<dim3(2500), blk, 0, stream>>>(xcur_f, xeb, h2, bo + ls * 256,
                                                     lng + (size_t)(l * 3 + s) * 256,
                                                     lnb + (size_t)(l * 3 + s) * 256,
                                                     last ? out : xbf, last ? nullptr : xbb);
            xcur_f = xbf; ++step;
        }
        gemm_lds<0, 64><<<gN256, blk, 0, stream>>>(xbb, wM + (size_t)l * 65536, h2, nullptr,
                                                   N_NODES, 256, 256, 0);
        bool last = (step == 14);
        ln_fused<<<dim3(2500), blk, 0, stream>>>(xcur_f, nullptr, h2, mlpb + (size_t)l * 256,
                                                 lng + (size_t)(l * 3 + 2) * 256,
                                                 lnb + (size_t)(l * 3 + 2) * 256,
                                                 last ? out : xbf, last ? nullptr : xbb);
        xcur_f = xbf; ++step;
    }
}